// Round 6
// baseline (19533.194 us; speedup 1.0000x reference)
//
#include <hip/hip_runtime.h>
#include <stdint.h>

// ---------------------------------------------------------------------------
// PointNet++ forward, MI355X. Round 11: L0 update-path micro-cuts.
//   - L0: k_fps11 = k_fps10 (single barrier, parity publish, per-center
//     prune, exact top-4 accept, qtop4 global reduce -- proven 12.39ms) with:
//     (a) progressive cv re-tightening: each center pass tracks the running
//         max mind (1 fused fmaxf/point); later centers test against the
//         tightened max -> strictly more provable-no-op skips, bit-exact.
//     (b) smind stored as float4 blocks [P/4][1024]: 4+4 ds_*_b128 at
//         16B/lane contiguous (conflict-free) instead of 32 scalar b32 ops.
//   - L1/L2: k_fps5 verbatim (unchanged, proven).
//   - selections bit-identical to sequential FPS at every level
//     (absmax must stay 0.003417969).
//   - k_prep / k_sort / k_sa / k_fp byte-identical to rounds 5-10.
// ---------------------------------------------------------------------------

#define DEV static __device__ __forceinline__

DEV float fadd_(float a, float b){ return __fadd_rn(a,b); }
DEV float fsub_(float a, float b){ return __fsub_rn(a,b); }
DEV float fmul_(float a, float b){ return __fmul_rn(a,b); }
DEV float fdiv_(float a, float b){ return __fdiv_rn(a,b); }

DEV float dot3(float ax,float ay,float az,float bx,float by,float bz){
  return fmaf(az,bz, fmaf(ay,by, __fmul_rn(ax,bx)));
}
DEV float sqd(float na, float nb, float d){
  float t = __fadd_rn(na, nb);
  float u = __fmul_rn(2.0f, d);
  return fmaxf(__fsub_rn(t, u), 0.0f);
}

// exact squared distance, same op pattern everywhere (selection determinism)
DEV float d2f_(float ax,float ay,float az,float bx,float by,float bz){
  float dx=fsub_(ax,bx), dy=fsub_(ay,by), dz=fsub_(az,bz);
  return fadd_(fadd_(fmul_(dx,dx),fmul_(dy,dy)),fmul_(dz,dz));
}
DEV float nrm3_(float x,float y,float z){
  return fadd_(fadd_(fmul_(x,x),fmul_(y,y)),fmul_(z,z));
}

// conservative point-to-bbox squared distance
DEV float bbd2(float sx,float sy,float sz,
               float lx,float ly,float lz,float hx,float hy,float hz){
  float dx = fmaxf(fmaxf(fsub_(lx,sx), fsub_(sx,hx)), 0.0f);
  float dy = fmaxf(fmaxf(fsub_(ly,sy), fsub_(sy,hy)), 0.0f);
  float dz = fmaxf(fmaxf(fsub_(lz,sz), fsub_(sz,hz)), 0.0f);
  return fadd_(fadd_(fmul_(dx,dx),fmul_(dy,dy)),fmul_(dz,dz));
}

DEV float rfl_f(float v){
  return __int_as_float(__builtin_amdgcn_readfirstlane(__float_as_int(v)));
}

// ---------------- DPP primitives -------------------------------------------
#define DPP0(src, ctrl, rm, bc) \
  __builtin_amdgcn_update_dpp(0, (int)(src), (ctrl), (rm), 0xf, (bc))

#define DPP64(dst, src, ctrl, rm, bc) { \
  uint32_t lo_ = (uint32_t)DPP0((uint32_t)(src), ctrl, rm, bc); \
  uint32_t hi_ = (uint32_t)DPP0((uint32_t)((src)>>32), ctrl, rm, bc); \
  (dst) = (((unsigned long long)hi_)<<32) | lo_; }

// ---- top-2 pair-merge (k_fps5, validated) ---------------------------------
#define MERGE2(A1, A2, ctrl, rm, bc) { \
  unsigned long long b1_, b2_, mn_, mx_; \
  DPP64(b1_, A1, ctrl, rm, bc); \
  DPP64(b2_, A2, ctrl, rm, bc); \
  mn_ = (A1) < b1_ ? (A1) : b1_; \
  mx_ = (A2) > b2_ ? (A2) : b2_; \
  (A1) = (A1) > b1_ ? (A1) : b1_; \
  (A2) = mn_ > mx_ ? mn_ : mx_; }

// ---- top-4 sorted-list bitonic merge --------------------------------------
#define MERGE4(A1,A2,A3,A4, ctrl, rm, bc) { \
  unsigned long long b1_,b2_,b3_,b4_, m1_,m2_,m3_,m4_, t_; \
  DPP64(b1_, A1, ctrl, rm, bc); \
  DPP64(b2_, A2, ctrl, rm, bc); \
  DPP64(b3_, A3, ctrl, rm, bc); \
  DPP64(b4_, A4, ctrl, rm, bc); \
  m1_ = (A1) > b4_ ? (A1) : b4_; \
  m2_ = (A2) > b3_ ? (A2) : b3_; \
  m3_ = (A3) > b2_ ? (A3) : b2_; \
  m4_ = (A4) > b1_ ? (A4) : b1_; \
  t_ = m1_ < m3_ ? m1_ : m3_;  m1_ = m1_ > m3_ ? m1_ : m3_;  m3_ = t_; \
  t_ = m2_ < m4_ ? m2_ : m4_;  m2_ = m2_ > m4_ ? m2_ : m4_;  m4_ = t_; \
  t_ = m1_ < m2_ ? m1_ : m2_;  m1_ = m1_ > m2_ ? m1_ : m2_;  m2_ = t_; \
  t_ = m3_ < m4_ ? m3_ : m4_;  m3_ = m3_ > m4_ ? m3_ : m4_;  m4_ = t_; \
  (A1)=m1_; (A2)=m2_; (A3)=m3_; (A4)=m4_; }

DEV unsigned long long rdlane64(unsigned long long v, int l){
  uint32_t lo=(uint32_t)__builtin_amdgcn_readlane((int)(uint32_t)v, l);
  uint32_t hi=(uint32_t)__builtin_amdgcn_readlane((int)(uint32_t)(v>>32), l);
  return (((unsigned long long)hi)<<32)|lo;
}

// 64-lane top-2 (k_fps5)
DEV void wtop2(unsigned long long &A1, unsigned long long &A2){
  MERGE2(A1,A2,0x111,0xf,true)
  MERGE2(A1,A2,0x112,0xf,true)
  MERGE2(A1,A2,0x114,0xf,true)
  MERGE2(A1,A2,0x118,0xf,true)
  MERGE2(A1,A2,0x142,0xa,false)
  MERGE2(A1,A2,0x143,0xc,false)
  A1 = rdlane64(A1,63); A2 = rdlane64(A2,63);
}
// 32-lane top-2 (k_fps5 global stage, lanes 0..31)
DEV void htop2(unsigned long long &A1, unsigned long long &A2){
  MERGE2(A1,A2,0x111,0xf,true)
  MERGE2(A1,A2,0x112,0xf,true)
  MERGE2(A1,A2,0x114,0xf,true)
  MERGE2(A1,A2,0x118,0xf,true)
  MERGE2(A1,A2,0x142,0xa,false)
  A1 = rdlane64(A1,31); A2 = rdlane64(A2,31);
}

// 64-lane top-4 (wave stage)
DEV void wtop4(unsigned long long &A1, unsigned long long &A2,
               unsigned long long &A3, unsigned long long &A4){
  MERGE4(A1,A2,A3,A4,0x111,0xf,true)
  MERGE4(A1,A2,A3,A4,0x112,0xf,true)
  MERGE4(A1,A2,A3,A4,0x114,0xf,true)
  MERGE4(A1,A2,A3,A4,0x118,0xf,true)
  MERGE4(A1,A2,A3,A4,0x142,0xa,false)
  MERGE4(A1,A2,A3,A4,0x143,0xc,false)
  A1 = rdlane64(A1,63); A2 = rdlane64(A2,63);
  A3 = rdlane64(A3,63); A4 = rdlane64(A4,63);
}

// 16-lane top-4 over 16 disjoint sorted-4 lists, lanes 0..15 (validated)
DEV void qtop4(unsigned long long &A1, unsigned long long &A2,
               unsigned long long &A3, unsigned long long &A4){
  MERGE4(A1,A2,A3,A4,0x111,0xf,true)
  MERGE4(A1,A2,A3,A4,0x112,0xf,true)
  MERGE4(A1,A2,A3,A4,0x114,0xf,true)
  MERGE4(A1,A2,A3,A4,0x118,0xf,true)
  A1 = rdlane64(A1,15); A2 = rdlane64(A2,15);
  A3 = rdlane64(A3,15); A4 = rdlane64(A4,15);
}

// ---------------------------------------------------------------------------
// prep: pos -> float4(x,y,z,|p|^2)  and  h0 = lin_in MLP(x)
// ---------------------------------------------------------------------------
__global__ __launch_bounds__(256) void k_prep(
    const float* __restrict__ x, const float* __restrict__ pos,
    const float* __restrict__ W0, const float* __restrict__ b0,
    const float* __restrict__ W1, const float* __restrict__ b1,
    float4* __restrict__ pos4, float* __restrict__ h_out, int n)
{
  __shared__ float sW0[256], sb0[16], sW1[256], sb1[16];
  int tid = threadIdx.x;
  sW0[tid] = W0[tid];
  sW1[tid] = W1[tid];
  if (tid < 16){ sb0[tid] = b0[tid]; sb1[tid] = b1[tid]; }
  __syncthreads();
  int p = blockIdx.x*256 + tid;
  if (p >= n) return;

  float px = pos[3*p], py = pos[3*p+1], pz = pos[3*p+2];
  float nrm = fadd_(fadd_(fmul_(px,px), fmul_(py,py)), fmul_(pz,pz));
  pos4[p] = make_float4(px,py,pz,nrm);

  const float4* xr = (const float4*)(x + (size_t)p*16);
  float4 v0 = xr[0], v1 = xr[1], v2 = xr[2], v3 = xr[3];
  float xin[16] = {v0.x,v0.y,v0.z,v0.w, v1.x,v1.y,v1.z,v1.w,
                   v2.x,v2.y,v2.z,v2.w, v3.x,v3.y,v3.z,v3.w};
  float h1[16];
  #pragma unroll
  for (int o=0;o<16;o++){
    float acc = fmul_(xin[0], sW0[o]);
    #pragma unroll
    for (int k=1;k<16;k++) acc = fmaf(xin[k], sW0[k*16+o], acc);
    h1[o] = fmaxf(fadd_(acc, sb0[o]), 0.0f);
  }
  float h2[16];
  #pragma unroll
  for (int o=0;o<16;o++){
    float acc = fmul_(h1[0], sW1[o]);
    #pragma unroll
    for (int k=1;k<16;k++) acc = fmaf(h1[k], sW1[k*16+o], acc);
    h2[o] = fmaxf(fadd_(acc, sb1[o]), 0.0f);
  }
  float4* hw = (float4*)(h_out + (size_t)p*16);
  hw[0] = make_float4(h2[0], h2[1], h2[2], h2[3]);
  hw[1] = make_float4(h2[4], h2[5], h2[6], h2[7]);
  hw[2] = make_float4(h2[8], h2[9], h2[10],h2[11]);
  hw[3] = make_float4(h2[12],h2[13],h2[14],h2[15]);
}

// ---------------------------------------------------------------------------
// k_sort: Morton counting sort (16^3 cells). Output w = bits(natural index).
// ---------------------------------------------------------------------------
DEV uint32_t expand4(uint32_t v){
  return (v&1u) | ((v&2u)<<2) | ((v&4u)<<4) | ((v&8u)<<6);
}
DEV int cellc(float v){
  int c = (int)(v*0.5f);
  return c < 0 ? 0 : (c > 15 ? 15 : c);
}
DEV uint32_t mkey(float4 p){
  return expand4((uint32_t)cellc(p.x))
       | (expand4((uint32_t)cellc(p.y))<<1)
       | (expand4((uint32_t)cellc(p.z))<<2);
}

__global__ __launch_bounds__(1024) void k_sort(
  const float4* __restrict__ nat, float4* __restrict__ srt,
  int* __restrict__ rank0, int n)
{
  __shared__ uint32_t hist[4096];
  __shared__ uint32_t gsum[1024];
  int tid = threadIdx.x;
  for (int i=tid;i<4096;i+=1024) hist[i]=0u;
  __syncthreads();
  for (int i=tid;i<n;i+=1024){
    float4 p = nat[i];
    atomicAdd(&hist[mkey(p)], 1u);
  }
  __syncthreads();
  uint32_t h0=hist[4*tid],h1=hist[4*tid+1],h2=hist[4*tid+2],h3=hist[4*tid+3];
  gsum[tid] = h0+h1+h2+h3;
  __syncthreads();
  for (int off=1; off<1024; off<<=1){
    uint32_t v = gsum[tid];
    uint32_t a = (tid>=off)? gsum[tid-off] : 0u;
    __syncthreads();
    gsum[tid] = v + a;
    __syncthreads();
  }
  uint32_t excl = (tid>0)? gsum[tid-1] : 0u;
  hist[4*tid]   = excl;
  hist[4*tid+1] = excl + h0;
  hist[4*tid+2] = excl + h0 + h1;
  hist[4*tid+3] = excl + h0 + h1 + h2;
  __syncthreads();
  for (int i=tid;i<n;i+=1024){
    float4 p = nat[i];
    uint32_t r = atomicAdd(&hist[mkey(p)], 1u);
    srt[r] = make_float4(p.x, p.y, p.z, __uint_as_float((uint32_t)i));
    if (i==0) *rank0 = (int)r;
  }
}

// ---------------------------------------------------------------------------
// k_fps11: L0 kernel. == k_fps10 with (a) progressive cv re-tightening in the
// per-center passes and (b) smind stored as float4 blocks [P/4][1024]
// (16B/lane contiguous ds_*_b128, conflict-free). Bit-exact selections.
// ---------------------------------------------------------------------------
template<int P>
__global__ __attribute__((amdgpu_waves_per_eu(4,4)))
__launch_bounds__(1024) void k_fps11(
    const float4* __restrict__ sp4,   // sorted points, w = bits(natidx)
    const int* __restrict__ rank0p,
    float4* __restrict__ samp,        // selection-order output, w = |p|^2
    int m)
{
  __shared__ __attribute__((aligned(16))) float4 smind4[(P/4)*1024];
  __shared__ __attribute__((aligned(16))) unsigned long long xch[2][64];
  const int t = threadIdx.x;
  const int lane = t & 63;
  const int w = t >> 6;

  float px[P], py[P], pz[P];
  uint32_t klo[P];
  float blox,bloy,bloz,bhix,bhiy,bhiz;
  #pragma unroll
  for (int k=0;k<P;k++){
    float4 p = sp4[t*P+k];
    px[k]=p.x; py[k]=p.y; pz[k]=p.z;
    uint32_t nat = __float_as_uint(p.w);
    klo[k] = ((0x3FFFu - nat)<<16) | (uint32_t)(t*P+k);
    if (k==0){ blox=bhix=p.x; bloy=bhiy=p.y; bloz=bhiz=p.z; }
    else {
      blox=fminf(blox,p.x); bhix=fmaxf(bhix,p.x);
      bloy=fminf(bloy,p.y); bhiy=fmaxf(bhiy,p.y);
      bloz=fminf(bloz,p.z); bhiz=fmaxf(bhiz,p.z);
    }
  }
  {
    float inf = __builtin_inff();
    #pragma unroll
    for (int kb=0;kb<P/4;kb++)
      smind4[kb*1024+t] = make_float4(inf,inf,inf,inf);
  }

  float c0x,c0y,c0z;
  float c1x=0.f,c1y=0.f,c1z=0.f, c2x=0.f,c2y=0.f,c2z=0.f;
  float c3x=0.f,c3y=0.f,c3z=0.f;
  {
    int r0 = *rank0p;
    float4 s0 = sp4[r0];
    c0x=s0.x; c0y=s0.y; c0z=s0.z;
    if (t==0){
      samp[0] = make_float4(s0.x,s0.y,s0.z, nrm3_(s0.x,s0.y,s0.z));
    }
  }
  __syncthreads();

  // thread top-4; hi=inf on tc1 forces a round-0 update for every thread
  unsigned long long tc1 = ((unsigned long long)0x7f800000u)<<32;
  unsigned long long tc2 = 0ull, tc3 = 0ull, tc4 = 0ull;
  // cached wave top-4 (valid after a wave's first update = round 0)
  unsigned long long a1=0ull,a2=0ull,a3=0ull,a4=0ull;

  int u = 1, sel = 1, round = 0;

  while (true){
    // ---- per-center bbox distances + gate (vs pre-update cv) -------------
    float cv = __uint_as_float((uint32_t)(tc1>>32));
    float dm0 = bbd2(c0x,c0y,c0z, blox,bloy,bloz,bhix,bhiy,bhiz);
    float dm1 = 0.f, dm2 = 0.f, dm3 = 0.f;
    bool act0 = fmul_(dm0, 0.99999f) < cv;
    bool updp = act0;
    if (u>1){ dm1 = bbd2(c1x,c1y,c1z, blox,bloy,bloz,bhix,bhiy,bhiz);
              updp |= (fmul_(dm1, 0.99999f) < cv); }
    if (u>2){ dm2 = bbd2(c2x,c2y,c2z, blox,bloy,bloz,bhix,bhiy,bhiz);
              updp |= (fmul_(dm2, 0.99999f) < cv); }
    if (u>3){ dm3 = bbd2(c3x,c3y,c3z, blox,bloy,bloz,bhix,bhiy,bhiz);
              updp |= (fmul_(dm3, 0.99999f) < cv); }
    // ---- update (per-center passes, progressively tightened) -------------
    if (__ballot(updp) != 0ull){
      if (updp){
        float nm[P];
        #pragma unroll
        for (int kb=0;kb<P/4;kb++){
          float4 v = smind4[kb*1024+t];
          nm[kb*4+0]=v.x; nm[kb*4+1]=v.y; nm[kb*4+2]=v.z; nm[kb*4+3]=v.w;
        }
        // curmax = current max mind; == cv until a pass runs, then tightened
        float curmax = cv;
        if (act0){
          float mx = 0.0f;
          #pragma unroll
          for (int k=0;k<P;k++){
            nm[k] = fminf(nm[k], d2f_(px[k],py[k],pz[k], c0x,c0y,c0z));
            mx = fmaxf(mx, nm[k]);
          }
          curmax = mx;
        }
        if (u>1){ if (fmul_(dm1, 0.99999f) < curmax){
          float mx = 0.0f;
          #pragma unroll
          for (int k=0;k<P;k++){
            nm[k] = fminf(nm[k], d2f_(px[k],py[k],pz[k], c1x,c1y,c1z));
            mx = fmaxf(mx, nm[k]);
          }
          curmax = mx;
        }}
        if (u>2){ if (fmul_(dm2, 0.99999f) < curmax){
          float mx = 0.0f;
          #pragma unroll
          for (int k=0;k<P;k++){
            nm[k] = fminf(nm[k], d2f_(px[k],py[k],pz[k], c2x,c2y,c2z));
            mx = fmaxf(mx, nm[k]);
          }
          curmax = mx;
        }}
        if (u>3){ if (fmul_(dm3, 0.99999f) < curmax){
          float mx = 0.0f;
          #pragma unroll
          for (int k=0;k<P;k++){
            nm[k] = fminf(nm[k], d2f_(px[k],py[k],pz[k], c3x,c3y,c3z));
            mx = fmaxf(mx, nm[k]);
          }
          curmax = mx;
        }}
        // rebuild thread top-4 (set-selection over 16 distinct keys)
        tc1 = 0ull; tc2 = 0ull; tc3 = 0ull; tc4 = 0ull;
        #pragma unroll
        for (int k=0;k<P;k++){
          unsigned long long key =
            (((unsigned long long)__float_as_uint(nm[k]))<<32) | klo[k];
          bool g1_ = key > tc1;
          bool g2_ = key > tc2;
          bool g3_ = key > tc3;
          bool g4_ = key > tc4;
          tc4 = g4_ ? (g3_ ? tc3 : key) : tc4;
          tc3 = g3_ ? (g2_ ? tc2 : key) : tc3;
          tc2 = g2_ ? (g1_ ? tc1 : key) : tc2;
          tc1 = g1_ ? key : tc1;
        }
        // write back (b128, conflict-free)
        #pragma unroll
        for (int kb=0;kb<P/4;kb++){
          smind4[kb*1024+t] =
            make_float4(nm[kb*4+0], nm[kb*4+1], nm[kb*4+2], nm[kb*4+3]);
        }
      }
      a1=tc1; a2=tc2; a3=tc3; a4=tc4;
      wtop4(a1,a2,a3,a4);           // wave-uniform sorted top-4
    }
    // ---- publish wave top-4 keys (every wave, every round) ---------------
    int par = round & 1;
    if (lane < 4){
      unsigned long long pv = (lane==0)?a1:((lane==1)?a2:((lane==2)?a3:a4));
      xch[par][w*4+lane] = pv;
    }
    __syncthreads();
    // ---- global top-4: 4 keys/lane over lanes 0..15, 4-stage merge -------
    unsigned long long g1v=0ull, g2v=0ull, g3v=0ull, g4v=0ull;
    if (lane < 16){
      const unsigned long long* b = &xch[par][lane*4];
      g1v=b[0]; g2v=b[1]; g3v=b[2]; g4v=b[3];
    }
    qtop4(g1v,g2v,g3v,g4v);
    // coords via sorted index in key low bits (uniform, L2-hot)
    float4 f1 = sp4[(int)(g1v & 0xFFFFull)];
    float4 f2 = sp4[(int)(g2v & 0xFFFFull)];
    float4 f3 = sp4[(int)(g3v & 0xFFFFull)];
    float4 f4 = sp4[(int)(g4v & 0xFFFFull)];
    float v2 = __uint_as_float((uint32_t)(g2v>>32));
    float v3 = __uint_as_float((uint32_t)(g3v>>32));
    float v4 = __uint_as_float((uint32_t)(g4v>>32));
    // ---- exact accept chain ----------------------------------------------
    float q12 = d2f_(f2.x,f2.y,f2.z, f1.x,f1.y,f1.z);
    bool acc2 = (sel+1 < m) && (q12 >= v2);
    float q13 = d2f_(f3.x,f3.y,f3.z, f1.x,f1.y,f1.z);
    float q23 = d2f_(f3.x,f3.y,f3.z, f2.x,f2.y,f2.z);
    bool acc3 = acc2 && (sel+2 < m) && (fminf(q13,q23) >= v3);
    float q14 = d2f_(f4.x,f4.y,f4.z, f1.x,f1.y,f1.z);
    float q24 = d2f_(f4.x,f4.y,f4.z, f2.x,f2.y,f2.z);
    float q34 = d2f_(f4.x,f4.y,f4.z, f3.x,f3.y,f3.z);
    bool acc4 = acc3 && (sel+3 < m) && (fminf(fminf(q14,q24),q34) >= v4);
    if (t==0)          samp[sel  ] = make_float4(f1.x,f1.y,f1.z, nrm3_(f1.x,f1.y,f1.z));
    if (acc2 && t==1)  samp[sel+1] = make_float4(f2.x,f2.y,f2.z, nrm3_(f2.x,f2.y,f2.z));
    if (acc3 && t==2)  samp[sel+2] = make_float4(f3.x,f3.y,f3.z, nrm3_(f3.x,f3.y,f3.z));
    if (acc4 && t==3)  samp[sel+3] = make_float4(f4.x,f4.y,f4.z, nrm3_(f4.x,f4.y,f4.z));
    int nacc = 1 + (acc2?1:0) + (acc3?1:0) + (acc4?1:0);
    sel += nacc; round++;
    if (sel >= m) break;
    // next-round centers in SGPRs (values are block-uniform)
    u   = __builtin_amdgcn_readfirstlane(nacc);
    c0x = rfl_f(f1.x); c0y = rfl_f(f1.y); c0z = rfl_f(f1.z);
    c1x = rfl_f(f2.x); c1y = rfl_f(f2.y); c1z = rfl_f(f2.z);
    c2x = rfl_f(f3.x); c2y = rfl_f(f3.y); c2z = rfl_f(f3.z);
    c3x = rfl_f(f4.x); c3y = rfl_f(f4.y); c3z = rfl_f(f4.z);
  }
}

// ---------------------------------------------------------------------------
// k_fps5: thread-parallel pruned FPS, top-2 batch (r0 baseline, verbatim).
// Used at L1/L2.
// ---------------------------------------------------------------------------
template<int P>
__global__ __attribute__((amdgpu_waves_per_eu(4,4)))
__launch_bounds__(1024) void k_fps5(
    const float4* __restrict__ sp4,   // sorted points, w = bits(natidx)
    const int* __restrict__ rank0p,
    float4* __restrict__ samp,        // selection-order output, w = |p|^2
    int m)
{
  __shared__ float smind[P*1024];
  __shared__ uint32_t xch[2][32*5];   // [parity][slot*5 + {klo,khi,x,y,z}]
  const int t = threadIdx.x;
  const int lane = t & 63;
  const int w = t >> 6;

  float px[P], py[P], pz[P];
  uint32_t klo[P];
  float blox,bloy,bloz,bhix,bhiy,bhiz;
  #pragma unroll
  for (int k=0;k<P;k++){
    float4 p = sp4[t*P+k];
    px[k]=p.x; py[k]=p.y; pz[k]=p.z;
    uint32_t nat = __float_as_uint(p.w);
    klo[k] = ((0x3FFFu - nat)<<16) | (uint32_t)(t*P+k);
    smind[k*1024+t] = __builtin_inff();
    if (k==0){ blox=bhix=p.x; bloy=bhiy=p.y; bloz=bhiz=p.z; }
    else {
      blox=fminf(blox,p.x); bhix=fmaxf(bhix,p.x);
      bloy=fminf(bloy,p.y); bhiy=fmaxf(bhiy,p.y);
      bloz=fminf(bloz,p.z); bhiz=fmaxf(bhiz,p.z);
    }
  }

  float c1x,c1y,c1z, c2x=0.f,c2y=0.f,c2z=0.f;
  {
    int r0 = *rank0p;
    float4 s0 = sp4[r0];
    c1x=s0.x; c1y=s0.y; c1z=s0.z;
    if (t==0){
      float nr = fadd_(fadd_(fmul_(s0.x,s0.x),fmul_(s0.y,s0.y)),fmul_(s0.z,s0.z));
      samp[0] = make_float4(s0.x,s0.y,s0.z,nr);
    }
  }
  __syncthreads();

  // thread champions; hi=inf forces round-0 update for every thread
  unsigned long long tc1 = ((unsigned long long)0x7f800000u)<<32, tc2 = 0ull;
  // cached owner slots (valid after round 0)
  bool own1 = false, own2 = false;
  uint32_t c1lo=0,c1hi=0, c2lo=0,c2hi=0;
  float o1x=0,o1y=0,o1z=0, o2x=0,o2y=0,o2z=0;

  int u2 = 0, sel = 1, round = 0;

  while (true){
    // ---- thread-local skip test ------------------------------------------
    bool updp;
    {
      float cv = __uint_as_float((uint32_t)(tc1>>32));
      float dm = bbd2(c1x,c1y,c1z, blox,bloy,bloz,bhix,bhiy,bhiz);
      if (u2){
        float dd = bbd2(c2x,c2y,c2z, blox,bloy,bloz,bhix,bhiy,bhiz);
        dm = fminf(dm, dd);
      }
      updp = (fmul_(dm, 0.99999f) < cv);
    }
    // ---- update + wave reduce + owner refresh only where needed ----------
    if (__ballot(updp) != 0ull){
      if (updp){
        tc1 = 0ull; tc2 = 0ull;
        #pragma unroll
        for (int k=0;k<P;k++){
          float dx=fsub_(px[k],c1x), dy=fsub_(py[k],c1y), dz=fsub_(pz[k],c1z);
          float da = fadd_(fadd_(fmul_(dx,dx),fmul_(dy,dy)),fmul_(dz,dz));
          float nm = fminf(smind[k*1024+t], da);
          if (u2){
            float ex=fsub_(px[k],c2x), ey=fsub_(py[k],c2y), ez=fsub_(pz[k],c2z);
            float db = fadd_(fadd_(fmul_(ex,ex),fmul_(ey,ey)),fmul_(ez,ez));
            nm = fminf(nm, db);
          }
          smind[k*1024+t] = nm;
          unsigned long long key =
            (((unsigned long long)__float_as_uint(nm))<<32) | klo[k];
          bool g1 = key > tc1;
          unsigned long long nt2 = g1 ? tc1 : (key > tc2 ? key : tc2);
          tc1 = g1 ? key : tc1;
          tc2 = nt2;
        }
      }
      unsigned long long a1 = tc1, a2 = tc2;
      wtop2(a1, a2);
      // refresh owner caches (whole wave)
      own1 = (tc1 == a1);
      own2 = (tc1 == a2) || (tc2 == a2);
      int kk1 = (int)(a1 & (unsigned long long)(P-1));
      int kk2 = (int)(a2 & (unsigned long long)(P-1));
      float sx1=px[0], sy1=py[0], sz1=pz[0];
      float sx2=px[0], sy2=py[0], sz2=pz[0];
      #pragma unroll
      for (int j=1;j<P;j++){
        bool e1=(j==kk1), e2=(j==kk2);
        sx1=e1?px[j]:sx1; sy1=e1?py[j]:sy1; sz1=e1?pz[j]:sz1;
        sx2=e2?px[j]:sx2; sy2=e2?py[j]:sy2; sz2=e2?pz[j]:sz2;
      }
      c1lo=(uint32_t)a1; c1hi=(uint32_t)(a1>>32); o1x=sx1; o1y=sy1; o1z=sz1;
      c2lo=(uint32_t)a2; c2hi=(uint32_t)(a2>>32); o2x=sx2; o2y=sy2; o2z=sz2;
    }
    // ---- publish wave candidates (owners rewrite every round) ------------
    int par = round & 1;
    if (own1){
      int b = (w*2)*5;
      xch[par][b]=c1lo; xch[par][b+1]=c1hi;
      xch[par][b+2]=__float_as_uint(o1x);
      xch[par][b+3]=__float_as_uint(o1y);
      xch[par][b+4]=__float_as_uint(o1z);
    }
    if (own2){
      int b = (w*2+1)*5;
      xch[par][b]=c2lo; xch[par][b+1]=c2hi;
      xch[par][b+2]=__float_as_uint(o2x);
      xch[par][b+3]=__float_as_uint(o2y);
      xch[par][b+4]=__float_as_uint(o2z);
    }
    __syncthreads();
    // ---- global top-2 over 32 slots (all waves redundantly) --------------
    unsigned long long cnd = 0ull;
    if (lane < 32){
      uint32_t lo = xch[par][lane*5], hi = xch[par][lane*5+1];
      cnd = (((unsigned long long)hi)<<32) | lo;
    }
    unsigned long long a1 = cnd, a2 = 0ull;
    htop2(a1, a2);
    unsigned long long b1 = __ballot(lane<32 && cnd==a1);
    unsigned long long b2 = __ballot(lane<32 && cnd==a2);
    int s1 = __ffsll(b1)-1;
    int s2 = __ffsll(b2)-1;
    float p1x=__uint_as_float(xch[par][s1*5+2]);
    float p1y=__uint_as_float(xch[par][s1*5+3]);
    float p1z=__uint_as_float(xch[par][s1*5+4]);
    float p2x=__uint_as_float(xch[par][s2*5+2]);
    float p2y=__uint_as_float(xch[par][s2*5+3]);
    float p2z=__uint_as_float(xch[par][s2*5+4]);
    float v2 = __uint_as_float((uint32_t)(a2>>32));
    // ---- exact double-accept ---------------------------------------------
    float qx=fsub_(p2x,p1x), qy=fsub_(p2y,p1y), qz=fsub_(p2z,p1z);
    float q  = fadd_(fadd_(fmul_(qx,qx),fmul_(qy,qy)),fmul_(qz,qz));
    bool acc2 = (sel+1 < m) && (q >= v2);
    if (t==0){
      float nr = fadd_(fadd_(fmul_(p1x,p1x),fmul_(p1y,p1y)),fmul_(p1z,p1z));
      samp[sel] = make_float4(p1x,p1y,p1z,nr);
    }
    if (acc2 && t==1){
      float nr = fadd_(fadd_(fmul_(p2x,p2x),fmul_(p2y,p2y)),fmul_(p2z,p2z));
      samp[sel+1] = make_float4(p2x,p2y,p2z,nr);
    }
    sel += acc2 ? 2 : 1;
    round++;
    if (sel >= m) break;
    c1x=p1x; c1y=p1y; c1z=p1z;
    u2 = acc2 ? 1 : 0;
    if (acc2){ c2x=p2x; c2y=p2y; c2z=p2z; }
  }
}

// ---------------------------------------------------------------------------
// SA: wave per target (unchanged)
// ---------------------------------------------------------------------------
#define SA_CAP 96

__global__ __launch_bounds__(256) void k_sa(
  const float4* __restrict__ spos, int n_src,
  const float4* __restrict__ tpos,
  const float*  __restrict__ F,
  const float* __restrict__ W0, const float* __restrict__ b0,
  const float* __restrict__ W1, const float* __restrict__ b1,
  float* __restrict__ Fout)
{
  __shared__ float sW0[361], sb0[19], sW1[304], sb1[16];
  __shared__ int   nidx[4][SA_CAP];
  __shared__ float nd2[4][SA_CAP];
  int tid = threadIdx.x;
  for (int i=tid;i<361;i+=256) sW0[i]=W0[i];
  for (int i=tid;i<304;i+=256) sW1[i]=W1[i];
  if (tid<19) sb0[tid]=b0[tid];
  if (tid<16) sb1[tid]=b1[tid];
  __syncthreads();

  int wv = tid >> 6, lane = tid & 63;
  int tg = blockIdx.x*4 + wv;
  float4 tp = tpos[tg];

  int cnt = 0;
  for (int base=0; base<n_src; base+=64){
    int j = base + lane;
    float4 sp = spos[j];
    float d2 = sqd(tp.w, sp.w, dot3(tp.x,tp.y,tp.z, sp.x,sp.y,sp.z));
    bool in = (d2 <= 4.0f);
    unsigned long long mk = __ballot(in);
    int pos = cnt + __popcll(mk & ((1ull<<lane)-1ull));
    if (in && pos < SA_CAP){ nidx[wv][pos]=j; nd2[wv][pos]=d2; }
    cnt += __popcll(mk);
  }
  if (cnt > SA_CAP) cnt = SA_CAP;

  if (cnt > 32){
    uint64_t tk0=0, tk1=0;
    for (int r=0;r<32;r++){
      float bvv = 3.5e38f; int bii = 0x7fffffff; int be = 0;
      for (int e=0;e<cnt;e++){
        bool done = (e<64) ? ((tk0>>e)&1ull) : ((tk1>>(e-64))&1ull);
        if (done) continue;
        float dv = nd2[wv][e]; int di = nidx[wv][e];
        if (dv < bvv || (dv == bvv && di < bii)){ bvv=dv; bii=di; be=e; }
      }
      if (be < 64) tk0 |= (1ull<<be); else tk1 |= (1ull<<(be-64));
    }
    int myi = 0; float myd = 0.0f;
    if (lane < 32){
      int seen = 0, sel = -1;
      for (int e=0;e<cnt && sel<0;e++){
        bool s = (e<64) ? ((tk0>>e)&1ull) : ((tk1>>(e-64))&1ull);
        if (s){ if (seen == lane) sel = e; seen++; }
      }
      myi = nidx[wv][sel]; myd = nd2[wv][sel];
    }
    __builtin_amdgcn_wave_barrier();
    if (lane < 32){ nidx[wv][lane]=myi; nd2[wv][lane]=myd; }
    __builtin_amdgcn_wave_barrier();
    cnt = 32;
  }

  float in19[19];
  #pragma unroll
  for (int k=0;k<19;k++) in19[k] = 0.0f;
  if (lane < cnt){
    int j = nidx[wv][lane];
    const float4* fr = (const float4*)(F + (size_t)j*16);
    float4 a=fr[0], b=fr[1], c=fr[2], d=fr[3];
    in19[0]=a.x; in19[1]=a.y; in19[2]=a.z; in19[3]=a.w;
    in19[4]=b.x; in19[5]=b.y; in19[6]=b.z; in19[7]=b.w;
    in19[8]=c.x; in19[9]=c.y; in19[10]=c.z; in19[11]=c.w;
    in19[12]=d.x; in19[13]=d.y; in19[14]=d.z; in19[15]=d.w;
    float4 sp = spos[j];
    in19[16]=fsub_(sp.x,tp.x); in19[17]=fsub_(sp.y,tp.y); in19[18]=fsub_(sp.z,tp.z);
  }
  float h[19];
  #pragma unroll
  for (int o=0;o<19;o++){
    float acc = fmul_(in19[0], sW0[o]);
    #pragma unroll
    for (int k=1;k<19;k++) acc = fmaf(in19[k], sW0[k*19+o], acc);
    h[o] = fmaxf(fadd_(acc, sb0[o]), 0.0f);
  }
  float outv[16];
  #pragma unroll
  for (int o=0;o<16;o++){
    float acc = fmul_(h[0], sW1[o]);
    #pragma unroll
    for (int k=1;k<19;k++) acc = fmaf(h[k], sW1[k*16+o], acc);
    float v = fmaxf(fadd_(acc, sb1[o]), 0.0f);
    outv[o] = (lane < cnt) ? v : -1e30f;
  }
  #pragma unroll
  for (int o=0;o<16;o++){
    float v = outv[o];
    #pragma unroll
    for (int s=1;s<64;s<<=1) v = fmaxf(v, __shfl_xor(v, s));
    outv[o] = v;
  }
  if (lane == 0){
    float4* dst = (float4*)(Fout + (size_t)tg*16);
    dst[0] = make_float4(outv[0], outv[1], outv[2], outv[3]);
    dst[1] = make_float4(outv[4], outv[5], outv[6], outv[7]);
    dst[2] = make_float4(outv[8], outv[9], outv[10],outv[11]);
    dst[3] = make_float4(outv[12],outv[13],outv[14],outv[15]);
  }
}

// ---------------------------------------------------------------------------
// FP: wave per fine point (unchanged)
// ---------------------------------------------------------------------------
__global__ __launch_bounds__(256) void k_fp(
  const float4* __restrict__ fpos,
  const float4* __restrict__ cpos, int n_coarse,
  const float* __restrict__ Fc, const float* __restrict__ Fs,
  const float* __restrict__ W0, const float* __restrict__ b0,
  const float* __restrict__ W1, const float* __restrict__ b1,
  const float* __restrict__ loW0, const float* __restrict__ lob0,
  const float* __restrict__ loW1, const float* __restrict__ lob1,
  float* __restrict__ outp, int final_)
{
  __shared__ float sW0[1024], sb0[32], sW1[512], sb1[16];
  __shared__ float sLW0[256], sLb0[16], sLW1[32], sLb1[2];
  int tid = threadIdx.x;
  for (int i=tid;i<1024;i+=256) sW0[i]=W0[i];
  for (int i=tid;i<512;i+=256)  sW1[i]=W1[i];
  if (tid<32) sb0[tid]=b0[tid];
  if (tid<16) sb1[tid]=b1[tid];
  if (final_){
    sLW0[tid & 255] = loW0[tid & 255];
    if (tid<16) sLb0[tid]=lob0[tid];
    if (tid<32) sLW1[tid]=loW1[tid];
    if (tid<2)  sLb1[tid]=lob1[tid];
  }
  __syncthreads();

  int wv = tid >> 6, lane = tid & 63;
  int f = blockIdx.x*4 + wv;
  float4 fp = fpos[f];

  float c0v=3.5e38f, c1v=3.5e38f, c2v=3.5e38f;
  int   c0i=0x7fffffff, c1i=0x7fffffff, c2i=0x7fffffff;
  for (int j=lane; j<n_coarse; j+=64){
    float4 cp = cpos[j];
    float d2 = sqd(fp.w, cp.w, dot3(fp.x,fp.y,fp.z, cp.x,cp.y,cp.z));
    if (d2 < c2v || (d2 == c2v && j < c2i)){
      bool a0 = (d2 < c0v) || (d2 == c0v && j < c0i);
      bool a1 = (d2 < c1v) || (d2 == c1v && j < c1i);
      c2v = a1 ? c1v : d2;               c2i = a1 ? c1i : j;
      c1v = a0 ? c0v : (a1 ? d2 : c1v);  c1i = a0 ? c0i : (a1 ? j : c1i);
      c0v = a0 ? d2 : c0v;               c0i = a0 ? j  : c0i;
    }
  }
  float nnd[3]; int nni[3];
  #pragma unroll
  for (int r=0;r<3;r++){
    float v = c0v; int idx = c0i;
    #pragma unroll
    for (int s=1;s<64;s<<=1){
      float ov = __shfl_xor(v, s);
      int   oi = __shfl_xor(idx, s);
      bool tk = (ov < v) || (ov == v && oi < idx);
      v = tk ? ov : v; idx = tk ? oi : idx;
    }
    nnd[r] = v; nni[r] = idx;
    if (c0v == v && c0i == idx){
      c0v=c1v; c0i=c1i; c1v=c2v; c1i=c2i; c2v=3.5e38f; c2i=0x7fffffff;
    }
  }
  float w0 = fdiv_(1.0f, fmaxf(nnd[0], 1e-16f));
  float w1 = fdiv_(1.0f, fmaxf(nnd[1], 1e-16f));
  float w2 = fdiv_(1.0f, fmaxf(nnd[2], 1e-16f));
  float ws = fadd_(fadd_(w0,w1),w2);
  w0 = fdiv_(w0,ws); w1 = fdiv_(w1,ws); w2 = fdiv_(w2,ws);

  float hv = 0.0f;
  if (lane < 16){
    int c = lane;
    float x0 = Fc[(size_t)nni[0]*16 + c];
    float x1 = Fc[(size_t)nni[1]*16 + c];
    float x2 = Fc[(size_t)nni[2]*16 + c];
    hv = fadd_(fadd_(fmul_(w0,x0), fmul_(w1,x1)), fmul_(w2,x2));
  } else if (lane < 32){
    hv = Fs[(size_t)f*16 + (lane-16)];
  }
  int o1 = lane & 31;
  float acc = fmul_(__shfl(hv, 0), sW0[o1]);
  #pragma unroll
  for (int k=1;k<32;k++) acc = fmaf(__shfl(hv, k), sW0[k*32+o1], acc);
  float g1 = fmaxf(fadd_(acc, sb0[o1]), 0.0f);
  int o2 = lane & 15;
  float a2 = fmul_(__shfl(g1, 0), sW1[o2]);
  #pragma unroll
  for (int k=1;k<32;k++) a2 = fmaf(__shfl(g1, k), sW1[k*16+o2], a2);
  float g2 = fmaxf(fadd_(a2, sb1[o2]), 0.0f);

  if (!final_){
    if (lane < 16) outp[(size_t)f*16 + lane] = g2;
  } else {
    float a3 = fmul_(__shfl(g2, 0), sLW0[o2]);
    #pragma unroll
    for (int k=1;k<16;k++) a3 = fmaf(__shfl(g2, k), sLW0[k*16+o2], a3);
    float q = fmaxf(fadd_(a3, sLb0[o2]), 0.0f);
    int o3 = lane & 1;
    float a4 = fmul_(__shfl(q, 0), sLW1[o3]);
    #pragma unroll
    for (int k=1;k<16;k++) a4 = fmaf(__shfl(q, k), sLW1[k*2+o3], a4);
    a4 = fadd_(a4, sLb1[o3]);
    if (lane < 2) outp[(size_t)f*2 + lane] = a4;
  }
}

// ---------------------------------------------------------------------------
extern "C" void kernel_launch(void* const* d_in, const int* in_sizes, int n_in,
                              void* d_out, int out_size, void* d_ws, size_t ws_size,
                              hipStream_t stream) {
  (void)in_sizes; (void)n_in; (void)out_size; (void)ws_size;
  const float* x     = (const float*)d_in[0];
  const float* pos   = (const float*)d_in[1];
  const float* liW0  = (const float*)d_in[3];
  const float* lib0  = (const float*)d_in[4];
  const float* liW1  = (const float*)d_in[5];
  const float* lib1  = (const float*)d_in[6];
  const float* saW0  = (const float*)d_in[7];
  const float* sab0  = (const float*)d_in[8];
  const float* saW1  = (const float*)d_in[9];
  const float* sab1  = (const float*)d_in[10];
  const float* fpW0  = (const float*)d_in[11];
  const float* fpb0  = (const float*)d_in[12];
  const float* fpW1  = (const float*)d_in[13];
  const float* fpb1  = (const float*)d_in[14];
  const float* loW0  = (const float*)d_in[15];
  const float* lob0  = (const float*)d_in[16];
  const float* loW1  = (const float*)d_in[17];
  const float* lob1  = (const float*)d_in[18];
  float* out = (float*)d_out;

  char* ws = (char*)d_ws;
  size_t off = 0;
  auto alloc = [&](size_t bytes)->void* {
    void* p = ws + off;
    off += (bytes + 255) & ~(size_t)255;
    return p;
  };
  float4* P0 = (float4*)alloc(16384u*16);
  float4* P1 = (float4*)alloc(8192u*16);
  float4* P2 = (float4*)alloc(4096u*16);
  float4* P3 = (float4*)alloc(2048u*16);
  float*  F0 = (float*)alloc(16384u*16*4);
  float*  F1 = (float*)alloc(8192u*16*4);
  float*  F2 = (float*)alloc(4096u*16*4);
  float*  F3 = (float*)alloc(2048u*16*4);
  float*  G2 = (float*)alloc(4096u*16*4);
  float*  G1 = (float*)alloc(8192u*16*4);
  float4* S0 = (float4*)alloc(16384u*16);
  float4* S1 = (float4*)alloc(8192u*16);
  float4* S2 = (float4*)alloc(4096u*16);
  int*    R0 = (int*)alloc(256);

  k_prep<<<64,256,0,stream>>>(x,pos, liW0,lib0,liW1,lib1, P0,F0, 16384);

  // SA path (sort -> FPS -> group+conv per level)
  k_sort<<<1,1024,0,stream>>>(P0, S0, R0+0, 16384);
  k_fps11<16><<<1,1024,0,stream>>>(S0, R0+0, P1, 8192);
  k_sa<<<2048,256,0,stream>>>(P0,16384, P1, F0, saW0,      sab0,    saW1,      sab1,    F1);
  k_sort<<<1,1024,0,stream>>>(P1, S1, R0+1, 8192);
  k_fps5<8><<<1,1024,0,stream>>>(S1, R0+1, P2, 4096);
  k_sa<<<1024,256,0,stream>>>(P1, 8192, P2, F1, saW0+361,  sab0+19, saW1+304,  sab1+16, F2);
  k_sort<<<1,1024,0,stream>>>(P2, S2, R0+2, 4096);
  k_fps5<4><<<1,1024,0,stream>>>(S2, R0+2, P3, 2048);
  k_sa<<< 512,256,0,stream>>>(P2, 4096, P3, F2, saW0+722,  sab0+38, saW1+608,  sab1+32, F3);

  // FP path
  k_fp<<<1024,256,0,stream>>>(P2, P3,2048, F3, F2,
      fpW0+2048, fpb0+64, fpW1+1024, fpb1+32,
      loW0,lob0,loW1,lob1, G2, 0);
  k_fp<<<2048,256,0,stream>>>(P1, P2,4096, G2, F1,
      fpW0+1024, fpb0+32, fpW1+512,  fpb1+16,
      loW0,lob0,loW1,lob1, G1, 0);
  k_fp<<<4096,256,0,stream>>>(P0, P1,8192, G1, F0,
      fpW0,      fpb0,    fpW1,      fpb1,
      loW0,lob0,loW1,lob1, out, 1);
}

// Round 7
// 19165.033 us; speedup vs baseline: 1.0192x; 1.0192x over previous
//
#include <hip/hip_runtime.h>
#include <stdint.h>

// ---------------------------------------------------------------------------
// PointNet++ forward, MI355X. Round 12: revert to round-10 configuration
// (session best, 19167us): L0 = k_fps10, L1/L2 = k_fps5.
//   - r11's bundled changes (progressive cv tightening + float4 smind)
//     regressed 12.39 -> 12.91ms with the scratch-spill signature
//     (FETCH 139->161KB, WRITE 136->172KB, VALUBusy down): nm[16] live
//     range stretched across 4 sequential passes spilled. Reverted.
//   - k_fps10: single barrier/round, parity publish, per-center prune,
//     exact top-4 batch accept, qtop4 global reduce (4 keys/lane over
//     lanes 0..15). Proven 12.39ms @ L0.
//   - k_fps5: top-2 batch, proven best at L1/L2 (small P: top-4's wider
//     touched-region outweighs its accept-rate gain).
//   - selections bit-identical to sequential FPS at every level
//     (absmax must stay 0.003417969).
// Remaining levers modeled flat/negative (top-8: accept-rate saturation;
// cheaper reduce: qtop4 is log-minimal; multi-CU: grid-barrier latency).
// ---------------------------------------------------------------------------

#define DEV static __device__ __forceinline__

DEV float fadd_(float a, float b){ return __fadd_rn(a,b); }
DEV float fsub_(float a, float b){ return __fsub_rn(a,b); }
DEV float fmul_(float a, float b){ return __fmul_rn(a,b); }
DEV float fdiv_(float a, float b){ return __fdiv_rn(a,b); }

DEV float dot3(float ax,float ay,float az,float bx,float by,float bz){
  return fmaf(az,bz, fmaf(ay,by, __fmul_rn(ax,bx)));
}
DEV float sqd(float na, float nb, float d){
  float t = __fadd_rn(na, nb);
  float u = __fmul_rn(2.0f, d);
  return fmaxf(__fsub_rn(t, u), 0.0f);
}

// exact squared distance, same op pattern everywhere (selection determinism)
DEV float d2f_(float ax,float ay,float az,float bx,float by,float bz){
  float dx=fsub_(ax,bx), dy=fsub_(ay,by), dz=fsub_(az,bz);
  return fadd_(fadd_(fmul_(dx,dx),fmul_(dy,dy)),fmul_(dz,dz));
}
DEV float nrm3_(float x,float y,float z){
  return fadd_(fadd_(fmul_(x,x),fmul_(y,y)),fmul_(z,z));
}

// conservative point-to-bbox squared distance
DEV float bbd2(float sx,float sy,float sz,
               float lx,float ly,float lz,float hx,float hy,float hz){
  float dx = fmaxf(fmaxf(fsub_(lx,sx), fsub_(sx,hx)), 0.0f);
  float dy = fmaxf(fmaxf(fsub_(ly,sy), fsub_(sy,hy)), 0.0f);
  float dz = fmaxf(fmaxf(fsub_(lz,sz), fsub_(sz,hz)), 0.0f);
  return fadd_(fadd_(fmul_(dx,dx),fmul_(dy,dy)),fmul_(dz,dz));
}

DEV float rfl_f(float v){
  return __int_as_float(__builtin_amdgcn_readfirstlane(__float_as_int(v)));
}

// ---------------- DPP primitives -------------------------------------------
#define DPP0(src, ctrl, rm, bc) \
  __builtin_amdgcn_update_dpp(0, (int)(src), (ctrl), (rm), 0xf, (bc))

#define DPP64(dst, src, ctrl, rm, bc) { \
  uint32_t lo_ = (uint32_t)DPP0((uint32_t)(src), ctrl, rm, bc); \
  uint32_t hi_ = (uint32_t)DPP0((uint32_t)((src)>>32), ctrl, rm, bc); \
  (dst) = (((unsigned long long)hi_)<<32) | lo_; }

// ---- top-2 pair-merge (k_fps5, validated) ---------------------------------
#define MERGE2(A1, A2, ctrl, rm, bc) { \
  unsigned long long b1_, b2_, mn_, mx_; \
  DPP64(b1_, A1, ctrl, rm, bc); \
  DPP64(b2_, A2, ctrl, rm, bc); \
  mn_ = (A1) < b1_ ? (A1) : b1_; \
  mx_ = (A2) > b2_ ? (A2) : b2_; \
  (A1) = (A1) > b1_ ? (A1) : b1_; \
  (A2) = mn_ > mx_ ? mn_ : mx_; }

// ---- top-4 sorted-list bitonic merge --------------------------------------
#define MERGE4(A1,A2,A3,A4, ctrl, rm, bc) { \
  unsigned long long b1_,b2_,b3_,b4_, m1_,m2_,m3_,m4_, t_; \
  DPP64(b1_, A1, ctrl, rm, bc); \
  DPP64(b2_, A2, ctrl, rm, bc); \
  DPP64(b3_, A3, ctrl, rm, bc); \
  DPP64(b4_, A4, ctrl, rm, bc); \
  m1_ = (A1) > b4_ ? (A1) : b4_; \
  m2_ = (A2) > b3_ ? (A2) : b3_; \
  m3_ = (A3) > b2_ ? (A3) : b2_; \
  m4_ = (A4) > b1_ ? (A4) : b1_; \
  t_ = m1_ < m3_ ? m1_ : m3_;  m1_ = m1_ > m3_ ? m1_ : m3_;  m3_ = t_; \
  t_ = m2_ < m4_ ? m2_ : m4_;  m2_ = m2_ > m4_ ? m2_ : m4_;  m4_ = t_; \
  t_ = m1_ < m2_ ? m1_ : m2_;  m1_ = m1_ > m2_ ? m1_ : m2_;  m2_ = t_; \
  t_ = m3_ < m4_ ? m3_ : m4_;  m3_ = m3_ > m4_ ? m3_ : m4_;  m4_ = t_; \
  (A1)=m1_; (A2)=m2_; (A3)=m3_; (A4)=m4_; }

DEV unsigned long long rdlane64(unsigned long long v, int l){
  uint32_t lo=(uint32_t)__builtin_amdgcn_readlane((int)(uint32_t)v, l);
  uint32_t hi=(uint32_t)__builtin_amdgcn_readlane((int)(uint32_t)(v>>32), l);
  return (((unsigned long long)hi)<<32)|lo;
}

// 64-lane top-2 (k_fps5)
DEV void wtop2(unsigned long long &A1, unsigned long long &A2){
  MERGE2(A1,A2,0x111,0xf,true)
  MERGE2(A1,A2,0x112,0xf,true)
  MERGE2(A1,A2,0x114,0xf,true)
  MERGE2(A1,A2,0x118,0xf,true)
  MERGE2(A1,A2,0x142,0xa,false)
  MERGE2(A1,A2,0x143,0xc,false)
  A1 = rdlane64(A1,63); A2 = rdlane64(A2,63);
}
// 32-lane top-2 (k_fps5 global stage, lanes 0..31)
DEV void htop2(unsigned long long &A1, unsigned long long &A2){
  MERGE2(A1,A2,0x111,0xf,true)
  MERGE2(A1,A2,0x112,0xf,true)
  MERGE2(A1,A2,0x114,0xf,true)
  MERGE2(A1,A2,0x118,0xf,true)
  MERGE2(A1,A2,0x142,0xa,false)
  A1 = rdlane64(A1,31); A2 = rdlane64(A2,31);
}

// 64-lane top-4 (k_fps10 wave stage)
DEV void wtop4(unsigned long long &A1, unsigned long long &A2,
               unsigned long long &A3, unsigned long long &A4){
  MERGE4(A1,A2,A3,A4,0x111,0xf,true)
  MERGE4(A1,A2,A3,A4,0x112,0xf,true)
  MERGE4(A1,A2,A3,A4,0x114,0xf,true)
  MERGE4(A1,A2,A3,A4,0x118,0xf,true)
  MERGE4(A1,A2,A3,A4,0x142,0xa,false)
  MERGE4(A1,A2,A3,A4,0x143,0xc,false)
  A1 = rdlane64(A1,63); A2 = rdlane64(A2,63);
  A3 = rdlane64(A3,63); A4 = rdlane64(A4,63);
}

// 16-lane top-4 over 16 disjoint sorted-4 lists, lanes 0..15 (validated)
DEV void qtop4(unsigned long long &A1, unsigned long long &A2,
               unsigned long long &A3, unsigned long long &A4){
  MERGE4(A1,A2,A3,A4,0x111,0xf,true)
  MERGE4(A1,A2,A3,A4,0x112,0xf,true)
  MERGE4(A1,A2,A3,A4,0x114,0xf,true)
  MERGE4(A1,A2,A3,A4,0x118,0xf,true)
  A1 = rdlane64(A1,15); A2 = rdlane64(A2,15);
  A3 = rdlane64(A3,15); A4 = rdlane64(A4,15);
}

// ---------------------------------------------------------------------------
// prep: pos -> float4(x,y,z,|p|^2)  and  h0 = lin_in MLP(x)
// ---------------------------------------------------------------------------
__global__ __launch_bounds__(256) void k_prep(
    const float* __restrict__ x, const float* __restrict__ pos,
    const float* __restrict__ W0, const float* __restrict__ b0,
    const float* __restrict__ W1, const float* __restrict__ b1,
    float4* __restrict__ pos4, float* __restrict__ h_out, int n)
{
  __shared__ float sW0[256], sb0[16], sW1[256], sb1[16];
  int tid = threadIdx.x;
  sW0[tid] = W0[tid];
  sW1[tid] = W1[tid];
  if (tid < 16){ sb0[tid] = b0[tid]; sb1[tid] = b1[tid]; }
  __syncthreads();
  int p = blockIdx.x*256 + tid;
  if (p >= n) return;

  float px = pos[3*p], py = pos[3*p+1], pz = pos[3*p+2];
  float nrm = fadd_(fadd_(fmul_(px,px), fmul_(py,py)), fmul_(pz,pz));
  pos4[p] = make_float4(px,py,pz,nrm);

  const float4* xr = (const float4*)(x + (size_t)p*16);
  float4 v0 = xr[0], v1 = xr[1], v2 = xr[2], v3 = xr[3];
  float xin[16] = {v0.x,v0.y,v0.z,v0.w, v1.x,v1.y,v1.z,v1.w,
                   v2.x,v2.y,v2.z,v2.w, v3.x,v3.y,v3.z,v3.w};
  float h1[16];
  #pragma unroll
  for (int o=0;o<16;o++){
    float acc = fmul_(xin[0], sW0[o]);
    #pragma unroll
    for (int k=1;k<16;k++) acc = fmaf(xin[k], sW0[k*16+o], acc);
    h1[o] = fmaxf(fadd_(acc, sb0[o]), 0.0f);
  }
  float h2[16];
  #pragma unroll
  for (int o=0;o<16;o++){
    float acc = fmul_(h1[0], sW1[o]);
    #pragma unroll
    for (int k=1;k<16;k++) acc = fmaf(h1[k], sW1[k*16+o], acc);
    h2[o] = fmaxf(fadd_(acc, sb1[o]), 0.0f);
  }
  float4* hw = (float4*)(h_out + (size_t)p*16);
  hw[0] = make_float4(h2[0], h2[1], h2[2], h2[3]);
  hw[1] = make_float4(h2[4], h2[5], h2[6], h2[7]);
  hw[2] = make_float4(h2[8], h2[9], h2[10],h2[11]);
  hw[3] = make_float4(h2[12],h2[13],h2[14],h2[15]);
}

// ---------------------------------------------------------------------------
// k_sort: Morton counting sort (16^3 cells). Output w = bits(natural index).
// ---------------------------------------------------------------------------
DEV uint32_t expand4(uint32_t v){
  return (v&1u) | ((v&2u)<<2) | ((v&4u)<<4) | ((v&8u)<<6);
}
DEV int cellc(float v){
  int c = (int)(v*0.5f);
  return c < 0 ? 0 : (c > 15 ? 15 : c);
}
DEV uint32_t mkey(float4 p){
  return expand4((uint32_t)cellc(p.x))
       | (expand4((uint32_t)cellc(p.y))<<1)
       | (expand4((uint32_t)cellc(p.z))<<2);
}

__global__ __launch_bounds__(1024) void k_sort(
  const float4* __restrict__ nat, float4* __restrict__ srt,
  int* __restrict__ rank0, int n)
{
  __shared__ uint32_t hist[4096];
  __shared__ uint32_t gsum[1024];
  int tid = threadIdx.x;
  for (int i=tid;i<4096;i+=1024) hist[i]=0u;
  __syncthreads();
  for (int i=tid;i<n;i+=1024){
    float4 p = nat[i];
    atomicAdd(&hist[mkey(p)], 1u);
  }
  __syncthreads();
  uint32_t h0=hist[4*tid],h1=hist[4*tid+1],h2=hist[4*tid+2],h3=hist[4*tid+3];
  gsum[tid] = h0+h1+h2+h3;
  __syncthreads();
  for (int off=1; off<1024; off<<=1){
    uint32_t v = gsum[tid];
    uint32_t a = (tid>=off)? gsum[tid-off] : 0u;
    __syncthreads();
    gsum[tid] = v + a;
    __syncthreads();
  }
  uint32_t excl = (tid>0)? gsum[tid-1] : 0u;
  hist[4*tid]   = excl;
  hist[4*tid+1] = excl + h0;
  hist[4*tid+2] = excl + h0 + h1;
  hist[4*tid+3] = excl + h0 + h1 + h2;
  __syncthreads();
  for (int i=tid;i<n;i+=1024){
    float4 p = nat[i];
    uint32_t r = atomicAdd(&hist[mkey(p)], 1u);
    srt[r] = make_float4(p.x, p.y, p.z, __uint_as_float((uint32_t)i));
    if (i==0) *rank0 = (int)r;
  }
}

// ---------------------------------------------------------------------------
// k_fps10: L0 kernel (P=16). Single barrier/round, parity publish, per-center
// prune, exact top-4 batch accept, qtop4 global reduce. Proven 12.39ms.
// Key = (float_bits(mind)<<32) | ((0x3FFF-natidx)<<16) | sortedidx.
// ---------------------------------------------------------------------------
template<int P>
__global__ __attribute__((amdgpu_waves_per_eu(4,4)))
__launch_bounds__(1024) void k_fps10(
    const float4* __restrict__ sp4,   // sorted points, w = bits(natidx)
    const int* __restrict__ rank0p,
    float4* __restrict__ samp,        // selection-order output, w = |p|^2
    int m)
{
  __shared__ float smind[P*1024];
  __shared__ __attribute__((aligned(16))) unsigned long long xch[2][64];
  const int t = threadIdx.x;
  const int lane = t & 63;
  const int w = t >> 6;

  float px[P], py[P], pz[P];
  uint32_t klo[P];
  float blox,bloy,bloz,bhix,bhiy,bhiz;
  #pragma unroll
  for (int k=0;k<P;k++){
    float4 p = sp4[t*P+k];
    px[k]=p.x; py[k]=p.y; pz[k]=p.z;
    uint32_t nat = __float_as_uint(p.w);
    klo[k] = ((0x3FFFu - nat)<<16) | (uint32_t)(t*P+k);
    smind[k*1024+t] = __builtin_inff();
    if (k==0){ blox=bhix=p.x; bloy=bhiy=p.y; bloz=bhiz=p.z; }
    else {
      blox=fminf(blox,p.x); bhix=fmaxf(bhix,p.x);
      bloy=fminf(bloy,p.y); bhiy=fmaxf(bhiy,p.y);
      bloz=fminf(bloz,p.z); bhiz=fmaxf(bhiz,p.z);
    }
  }

  float c0x,c0y,c0z;
  float c1x=0.f,c1y=0.f,c1z=0.f, c2x=0.f,c2y=0.f,c2z=0.f;
  float c3x=0.f,c3y=0.f,c3z=0.f;
  {
    int r0 = *rank0p;
    float4 s0 = sp4[r0];
    c0x=s0.x; c0y=s0.y; c0z=s0.z;
    if (t==0){
      samp[0] = make_float4(s0.x,s0.y,s0.z, nrm3_(s0.x,s0.y,s0.z));
    }
  }
  __syncthreads();

  // thread top-4; hi=inf on tc1 forces a round-0 update for every thread
  unsigned long long tc1 = ((unsigned long long)0x7f800000u)<<32;
  unsigned long long tc2 = 0ull, tc3 = 0ull, tc4 = 0ull;
  // cached wave top-4 (valid after a wave's first update = round 0)
  unsigned long long a1=0ull,a2=0ull,a3=0ull,a4=0ull;

  int u = 1, sel = 1, round = 0;

  while (true){
    // ---- per-center thread-local skip tests ------------------------------
    float cv = __uint_as_float((uint32_t)(tc1>>32));
    bool act0, act1=false, act2=false, act3=false;
    act0 = fmul_(bbd2(c0x,c0y,c0z, blox,bloy,bloz,bhix,bhiy,bhiz), 0.99999f) < cv;
    if (u>1) act1 = fmul_(bbd2(c1x,c1y,c1z, blox,bloy,bloz,bhix,bhiy,bhiz), 0.99999f) < cv;
    if (u>2) act2 = fmul_(bbd2(c2x,c2y,c2z, blox,bloy,bloz,bhix,bhiy,bhiz), 0.99999f) < cv;
    if (u>3) act3 = fmul_(bbd2(c3x,c3y,c3z, blox,bloy,bloz,bhix,bhiy,bhiz), 0.99999f) < cv;
    bool updp = act0 | act1 | act2 | act3;
    // ---- update (per-center passes) + wave top-4 only where needed -------
    if (__ballot(updp) != 0ull){
      if (updp){
        float nm[P];
        #pragma unroll
        for (int k=0;k<P;k++) nm[k] = smind[k*1024+t];
        if (act0){
          #pragma unroll
          for (int k=0;k<P;k++)
            nm[k] = fminf(nm[k], d2f_(px[k],py[k],pz[k], c0x,c0y,c0z));
        }
        if (u>1){ if (act1){
          #pragma unroll
          for (int k=0;k<P;k++)
            nm[k] = fminf(nm[k], d2f_(px[k],py[k],pz[k], c1x,c1y,c1z));
        }}
        if (u>2){ if (act2){
          #pragma unroll
          for (int k=0;k<P;k++)
            nm[k] = fminf(nm[k], d2f_(px[k],py[k],pz[k], c2x,c2y,c2z));
        }}
        if (u>3){ if (act3){
          #pragma unroll
          for (int k=0;k<P;k++)
            nm[k] = fminf(nm[k], d2f_(px[k],py[k],pz[k], c3x,c3y,c3z));
        }}
        tc1 = 0ull; tc2 = 0ull; tc3 = 0ull; tc4 = 0ull;
        #pragma unroll
        for (int k=0;k<P;k++){
          smind[k*1024+t] = nm[k];
          unsigned long long key =
            (((unsigned long long)__float_as_uint(nm[k]))<<32) | klo[k];
          bool g1_ = key > tc1;
          bool g2_ = key > tc2;
          bool g3_ = key > tc3;
          bool g4_ = key > tc4;
          tc4 = g4_ ? (g3_ ? tc3 : key) : tc4;
          tc3 = g3_ ? (g2_ ? tc2 : key) : tc3;
          tc2 = g2_ ? (g1_ ? tc1 : key) : tc2;
          tc1 = g1_ ? key : tc1;
        }
      }
      a1=tc1; a2=tc2; a3=tc3; a4=tc4;
      wtop4(a1,a2,a3,a4);           // wave-uniform sorted top-4
    }
    // ---- publish wave top-4 keys (every wave, every round) ---------------
    int par = round & 1;
    if (lane < 4){
      unsigned long long pv = (lane==0)?a1:((lane==1)?a2:((lane==2)?a3:a4));
      xch[par][w*4+lane] = pv;
    }
    __syncthreads();
    // ---- global top-4: 4 keys/lane over lanes 0..15, 4-stage merge -------
    unsigned long long g1v=0ull, g2v=0ull, g3v=0ull, g4v=0ull;
    if (lane < 16){
      const unsigned long long* b = &xch[par][lane*4];
      g1v=b[0]; g2v=b[1]; g3v=b[2]; g4v=b[3];
    }
    qtop4(g1v,g2v,g3v,g4v);
    // coords via sorted index in key low bits (uniform, L2-hot)
    float4 f1 = sp4[(int)(g1v & 0xFFFFull)];
    float4 f2 = sp4[(int)(g2v & 0xFFFFull)];
    float4 f3 = sp4[(int)(g3v & 0xFFFFull)];
    float4 f4 = sp4[(int)(g4v & 0xFFFFull)];
    float v2 = __uint_as_float((uint32_t)(g2v>>32));
    float v3 = __uint_as_float((uint32_t)(g3v>>32));
    float v4 = __uint_as_float((uint32_t)(g4v>>32));
    // ---- exact accept chain ----------------------------------------------
    float q12 = d2f_(f2.x,f2.y,f2.z, f1.x,f1.y,f1.z);
    bool acc2 = (sel+1 < m) && (q12 >= v2);
    float q13 = d2f_(f3.x,f3.y,f3.z, f1.x,f1.y,f1.z);
    float q23 = d2f_(f3.x,f3.y,f3.z, f2.x,f2.y,f2.z);
    bool acc3 = acc2 && (sel+2 < m) && (fminf(q13,q23) >= v3);
    float q14 = d2f_(f4.x,f4.y,f4.z, f1.x,f1.y,f1.z);
    float q24 = d2f_(f4.x,f4.y,f4.z, f2.x,f2.y,f2.z);
    float q34 = d2f_(f4.x,f4.y,f4.z, f3.x,f3.y,f3.z);
    bool acc4 = acc3 && (sel+3 < m) && (fminf(fminf(q14,q24),q34) >= v4);
    if (t==0)          samp[sel  ] = make_float4(f1.x,f1.y,f1.z, nrm3_(f1.x,f1.y,f1.z));
    if (acc2 && t==1)  samp[sel+1] = make_float4(f2.x,f2.y,f2.z, nrm3_(f2.x,f2.y,f2.z));
    if (acc3 && t==2)  samp[sel+2] = make_float4(f3.x,f3.y,f3.z, nrm3_(f3.x,f3.y,f3.z));
    if (acc4 && t==3)  samp[sel+3] = make_float4(f4.x,f4.y,f4.z, nrm3_(f4.x,f4.y,f4.z));
    int nacc = 1 + (acc2?1:0) + (acc3?1:0) + (acc4?1:0);
    sel += nacc; round++;
    if (sel >= m) break;
    // next-round centers in SGPRs (values are block-uniform)
    u   = __builtin_amdgcn_readfirstlane(nacc);
    c0x = rfl_f(f1.x); c0y = rfl_f(f1.y); c0z = rfl_f(f1.z);
    c1x = rfl_f(f2.x); c1y = rfl_f(f2.y); c1z = rfl_f(f2.z);
    c2x = rfl_f(f3.x); c2y = rfl_f(f3.y); c2z = rfl_f(f3.z);
    c3x = rfl_f(f4.x); c3y = rfl_f(f4.y); c3z = rfl_f(f4.z);
  }
}

// ---------------------------------------------------------------------------
// k_fps5: thread-parallel pruned FPS, top-2 batch (r0 baseline, verbatim).
// Used at L1/L2.
// ---------------------------------------------------------------------------
template<int P>
__global__ __attribute__((amdgpu_waves_per_eu(4,4)))
__launch_bounds__(1024) void k_fps5(
    const float4* __restrict__ sp4,   // sorted points, w = bits(natidx)
    const int* __restrict__ rank0p,
    float4* __restrict__ samp,        // selection-order output, w = |p|^2
    int m)
{
  __shared__ float smind[P*1024];
  __shared__ uint32_t xch[2][32*5];   // [parity][slot*5 + {klo,khi,x,y,z}]
  const int t = threadIdx.x;
  const int lane = t & 63;
  const int w = t >> 6;

  float px[P], py[P], pz[P];
  uint32_t klo[P];
  float blox,bloy,bloz,bhix,bhiy,bhiz;
  #pragma unroll
  for (int k=0;k<P;k++){
    float4 p = sp4[t*P+k];
    px[k]=p.x; py[k]=p.y; pz[k]=p.z;
    uint32_t nat = __float_as_uint(p.w);
    klo[k] = ((0x3FFFu - nat)<<16) | (uint32_t)(t*P+k);
    smind[k*1024+t] = __builtin_inff();
    if (k==0){ blox=bhix=p.x; bloy=bhiy=p.y; bloz=bhiz=p.z; }
    else {
      blox=fminf(blox,p.x); bhix=fmaxf(bhix,p.x);
      bloy=fminf(bloy,p.y); bhiy=fmaxf(bhiy,p.y);
      bloz=fminf(bloz,p.z); bhiz=fmaxf(bhiz,p.z);
    }
  }

  float c1x,c1y,c1z, c2x=0.f,c2y=0.f,c2z=0.f;
  {
    int r0 = *rank0p;
    float4 s0 = sp4[r0];
    c1x=s0.x; c1y=s0.y; c1z=s0.z;
    if (t==0){
      float nr = fadd_(fadd_(fmul_(s0.x,s0.x),fmul_(s0.y,s0.y)),fmul_(s0.z,s0.z));
      samp[0] = make_float4(s0.x,s0.y,s0.z,nr);
    }
  }
  __syncthreads();

  // thread champions; hi=inf forces round-0 update for every thread
  unsigned long long tc1 = ((unsigned long long)0x7f800000u)<<32, tc2 = 0ull;
  // cached owner slots (valid after round 0)
  bool own1 = false, own2 = false;
  uint32_t c1lo=0,c1hi=0, c2lo=0,c2hi=0;
  float o1x=0,o1y=0,o1z=0, o2x=0,o2y=0,o2z=0;

  int u2 = 0, sel = 1, round = 0;

  while (true){
    // ---- thread-local skip test ------------------------------------------
    bool updp;
    {
      float cv = __uint_as_float((uint32_t)(tc1>>32));
      float dm = bbd2(c1x,c1y,c1z, blox,bloy,bloz,bhix,bhiy,bhiz);
      if (u2){
        float dd = bbd2(c2x,c2y,c2z, blox,bloy,bloz,bhix,bhiy,bhiz);
        dm = fminf(dm, dd);
      }
      updp = (fmul_(dm, 0.99999f) < cv);
    }
    // ---- update + wave reduce + owner refresh only where needed ----------
    if (__ballot(updp) != 0ull){
      if (updp){
        tc1 = 0ull; tc2 = 0ull;
        #pragma unroll
        for (int k=0;k<P;k++){
          float dx=fsub_(px[k],c1x), dy=fsub_(py[k],c1y), dz=fsub_(pz[k],c1z);
          float da = fadd_(fadd_(fmul_(dx,dx),fmul_(dy,dy)),fmul_(dz,dz));
          float nm = fminf(smind[k*1024+t], da);
          if (u2){
            float ex=fsub_(px[k],c2x), ey=fsub_(py[k],c2y), ez=fsub_(pz[k],c2z);
            float db = fadd_(fadd_(fmul_(ex,ex),fmul_(ey,ey)),fmul_(ez,ez));
            nm = fminf(nm, db);
          }
          smind[k*1024+t] = nm;
          unsigned long long key =
            (((unsigned long long)__float_as_uint(nm))<<32) | klo[k];
          bool g1 = key > tc1;
          unsigned long long nt2 = g1 ? tc1 : (key > tc2 ? key : tc2);
          tc1 = g1 ? key : tc1;
          tc2 = nt2;
        }
      }
      unsigned long long a1 = tc1, a2 = tc2;
      wtop2(a1, a2);
      // refresh owner caches (whole wave)
      own1 = (tc1 == a1);
      own2 = (tc1 == a2) || (tc2 == a2);
      int kk1 = (int)(a1 & (unsigned long long)(P-1));
      int kk2 = (int)(a2 & (unsigned long long)(P-1));
      float sx1=px[0], sy1=py[0], sz1=pz[0];
      float sx2=px[0], sy2=py[0], sz2=pz[0];
      #pragma unroll
      for (int j=1;j<P;j++){
        bool e1=(j==kk1), e2=(j==kk2);
        sx1=e1?px[j]:sx1; sy1=e1?py[j]:sy1; sz1=e1?pz[j]:sz1;
        sx2=e2?px[j]:sx2; sy2=e2?py[j]:sy2; sz2=e2?pz[j]:sz2;
      }
      c1lo=(uint32_t)a1; c1hi=(uint32_t)(a1>>32); o1x=sx1; o1y=sy1; o1z=sz1;
      c2lo=(uint32_t)a2; c2hi=(uint32_t)(a2>>32); o2x=sx2; o2y=sy2; o2z=sz2;
    }
    // ---- publish wave candidates (owners rewrite every round) ------------
    int par = round & 1;
    if (own1){
      int b = (w*2)*5;
      xch[par][b]=c1lo; xch[par][b+1]=c1hi;
      xch[par][b+2]=__float_as_uint(o1x);
      xch[par][b+3]=__float_as_uint(o1y);
      xch[par][b+4]=__float_as_uint(o1z);
    }
    if (own2){
      int b = (w*2+1)*5;
      xch[par][b]=c2lo; xch[par][b+1]=c2hi;
      xch[par][b+2]=__float_as_uint(o2x);
      xch[par][b+3]=__float_as_uint(o2y);
      xch[par][b+4]=__float_as_uint(o2z);
    }
    __syncthreads();
    // ---- global top-2 over 32 slots (all waves redundantly) --------------
    unsigned long long cnd = 0ull;
    if (lane < 32){
      uint32_t lo = xch[par][lane*5], hi = xch[par][lane*5+1];
      cnd = (((unsigned long long)hi)<<32) | lo;
    }
    unsigned long long a1 = cnd, a2 = 0ull;
    htop2(a1, a2);
    unsigned long long b1 = __ballot(lane<32 && cnd==a1);
    unsigned long long b2 = __ballot(lane<32 && cnd==a2);
    int s1 = __ffsll(b1)-1;
    int s2 = __ffsll(b2)-1;
    float p1x=__uint_as_float(xch[par][s1*5+2]);
    float p1y=__uint_as_float(xch[par][s1*5+3]);
    float p1z=__uint_as_float(xch[par][s1*5+4]);
    float p2x=__uint_as_float(xch[par][s2*5+2]);
    float p2y=__uint_as_float(xch[par][s2*5+3]);
    float p2z=__uint_as_float(xch[par][s2*5+4]);
    float v2 = __uint_as_float((uint32_t)(a2>>32));
    // ---- exact double-accept ---------------------------------------------
    float qx=fsub_(p2x,p1x), qy=fsub_(p2y,p1y), qz=fsub_(p2z,p1z);
    float q  = fadd_(fadd_(fmul_(qx,qx),fmul_(qy,qy)),fmul_(qz,qz));
    bool acc2 = (sel+1 < m) && (q >= v2);
    if (t==0){
      float nr = fadd_(fadd_(fmul_(p1x,p1x),fmul_(p1y,p1y)),fmul_(p1z,p1z));
      samp[sel] = make_float4(p1x,p1y,p1z,nr);
    }
    if (acc2 && t==1){
      float nr = fadd_(fadd_(fmul_(p2x,p2x),fmul_(p2y,p2y)),fmul_(p2z,p2z));
      samp[sel+1] = make_float4(p2x,p2y,p2z,nr);
    }
    sel += acc2 ? 2 : 1;
    round++;
    if (sel >= m) break;
    c1x=p1x; c1y=p1y; c1z=p1z;
    u2 = acc2 ? 1 : 0;
    if (acc2){ c2x=p2x; c2y=p2y; c2z=p2z; }
  }
}

// ---------------------------------------------------------------------------
// SA: wave per target (unchanged)
// ---------------------------------------------------------------------------
#define SA_CAP 96

__global__ __launch_bounds__(256) void k_sa(
  const float4* __restrict__ spos, int n_src,
  const float4* __restrict__ tpos,
  const float*  __restrict__ F,
  const float* __restrict__ W0, const float* __restrict__ b0,
  const float* __restrict__ W1, const float* __restrict__ b1,
  float* __restrict__ Fout)
{
  __shared__ float sW0[361], sb0[19], sW1[304], sb1[16];
  __shared__ int   nidx[4][SA_CAP];
  __shared__ float nd2[4][SA_CAP];
  int tid = threadIdx.x;
  for (int i=tid;i<361;i+=256) sW0[i]=W0[i];
  for (int i=tid;i<304;i+=256) sW1[i]=W1[i];
  if (tid<19) sb0[tid]=b0[tid];
  if (tid<16) sb1[tid]=b1[tid];
  __syncthreads();

  int wv = tid >> 6, lane = tid & 63;
  int tg = blockIdx.x*4 + wv;
  float4 tp = tpos[tg];

  int cnt = 0;
  for (int base=0; base<n_src; base+=64){
    int j = base + lane;
    float4 sp = spos[j];
    float d2 = sqd(tp.w, sp.w, dot3(tp.x,tp.y,tp.z, sp.x,sp.y,sp.z));
    bool in = (d2 <= 4.0f);
    unsigned long long mk = __ballot(in);
    int pos = cnt + __popcll(mk & ((1ull<<lane)-1ull));
    if (in && pos < SA_CAP){ nidx[wv][pos]=j; nd2[wv][pos]=d2; }
    cnt += __popcll(mk);
  }
  if (cnt > SA_CAP) cnt = SA_CAP;

  if (cnt > 32){
    uint64_t tk0=0, tk1=0;
    for (int r=0;r<32;r++){
      float bvv = 3.5e38f; int bii = 0x7fffffff; int be = 0;
      for (int e=0;e<cnt;e++){
        bool done = (e<64) ? ((tk0>>e)&1ull) : ((tk1>>(e-64))&1ull);
        if (done) continue;
        float dv = nd2[wv][e]; int di = nidx[wv][e];
        if (dv < bvv || (dv == bvv && di < bii)){ bvv=dv; bii=di; be=e; }
      }
      if (be < 64) tk0 |= (1ull<<be); else tk1 |= (1ull<<(be-64));
    }
    int myi = 0; float myd = 0.0f;
    if (lane < 32){
      int seen = 0, sel = -1;
      for (int e=0;e<cnt && sel<0;e++){
        bool s = (e<64) ? ((tk0>>e)&1ull) : ((tk1>>(e-64))&1ull);
        if (s){ if (seen == lane) sel = e; seen++; }
      }
      myi = nidx[wv][sel]; myd = nd2[wv][sel];
    }
    __builtin_amdgcn_wave_barrier();
    if (lane < 32){ nidx[wv][lane]=myi; nd2[wv][lane]=myd; }
    __builtin_amdgcn_wave_barrier();
    cnt = 32;
  }

  float in19[19];
  #pragma unroll
  for (int k=0;k<19;k++) in19[k] = 0.0f;
  if (lane < cnt){
    int j = nidx[wv][lane];
    const float4* fr = (const float4*)(F + (size_t)j*16);
    float4 a=fr[0], b=fr[1], c=fr[2], d=fr[3];
    in19[0]=a.x; in19[1]=a.y; in19[2]=a.z; in19[3]=a.w;
    in19[4]=b.x; in19[5]=b.y; in19[6]=b.z; in19[7]=b.w;
    in19[8]=c.x; in19[9]=c.y; in19[10]=c.z; in19[11]=c.w;
    in19[12]=d.x; in19[13]=d.y; in19[14]=d.z; in19[15]=d.w;
    float4 sp = spos[j];
    in19[16]=fsub_(sp.x,tp.x); in19[17]=fsub_(sp.y,tp.y); in19[18]=fsub_(sp.z,tp.z);
  }
  float h[19];
  #pragma unroll
  for (int o=0;o<19;o++){
    float acc = fmul_(in19[0], sW0[o]);
    #pragma unroll
    for (int k=1;k<19;k++) acc = fmaf(in19[k], sW0[k*19+o], acc);
    h[o] = fmaxf(fadd_(acc, sb0[o]), 0.0f);
  }
  float outv[16];
  #pragma unroll
  for (int o=0;o<16;o++){
    float acc = fmul_(h[0], sW1[o]);
    #pragma unroll
    for (int k=1;k<19;k++) acc = fmaf(h[k], sW1[k*16+o], acc);
    float v = fmaxf(fadd_(acc, sb1[o]), 0.0f);
    outv[o] = (lane < cnt) ? v : -1e30f;
  }
  #pragma unroll
  for (int o=0;o<16;o++){
    float v = outv[o];
    #pragma unroll
    for (int s=1;s<64;s<<=1) v = fmaxf(v, __shfl_xor(v, s));
    outv[o] = v;
  }
  if (lane == 0){
    float4* dst = (float4*)(Fout + (size_t)tg*16);
    dst[0] = make_float4(outv[0], outv[1], outv[2], outv[3]);
    dst[1] = make_float4(outv[4], outv[5], outv[6], outv[7]);
    dst[2] = make_float4(outv[8], outv[9], outv[10],outv[11]);
    dst[3] = make_float4(outv[12],outv[13],outv[14],outv[15]);
  }
}

// ---------------------------------------------------------------------------
// FP: wave per fine point (unchanged)
// ---------------------------------------------------------------------------
__global__ __launch_bounds__(256) void k_fp(
  const float4* __restrict__ fpos,
  const float4* __restrict__ cpos, int n_coarse,
  const float* __restrict__ Fc, const float* __restrict__ Fs,
  const float* __restrict__ W0, const float* __restrict__ b0,
  const float* __restrict__ W1, const float* __restrict__ b1,
  const float* __restrict__ loW0, const float* __restrict__ lob0,
  const float* __restrict__ loW1, const float* __restrict__ lob1,
  float* __restrict__ outp, int final_)
{
  __shared__ float sW0[1024], sb0[32], sW1[512], sb1[16];
  __shared__ float sLW0[256], sLb0[16], sLW1[32], sLb1[2];
  int tid = threadIdx.x;
  for (int i=tid;i<1024;i+=256) sW0[i]=W0[i];
  for (int i=tid;i<512;i+=256)  sW1[i]=W1[i];
  if (tid<32) sb0[tid]=b0[tid];
  if (tid<16) sb1[tid]=b1[tid];
  if (final_){
    sLW0[tid & 255] = loW0[tid & 255];
    if (tid<16) sLb0[tid]=lob0[tid];
    if (tid<32) sLW1[tid]=loW1[tid];
    if (tid<2)  sLb1[tid]=lob1[tid];
  }
  __syncthreads();

  int wv = tid >> 6, lane = tid & 63;
  int f = blockIdx.x*4 + wv;
  float4 fp = fpos[f];

  float c0v=3.5e38f, c1v=3.5e38f, c2v=3.5e38f;
  int   c0i=0x7fffffff, c1i=0x7fffffff, c2i=0x7fffffff;
  for (int j=lane; j<n_coarse; j+=64){
    float4 cp = cpos[j];
    float d2 = sqd(fp.w, cp.w, dot3(fp.x,fp.y,fp.z, cp.x,cp.y,cp.z));
    if (d2 < c2v || (d2 == c2v && j < c2i)){
      bool a0 = (d2 < c0v) || (d2 == c0v && j < c0i);
      bool a1 = (d2 < c1v) || (d2 == c1v && j < c1i);
      c2v = a1 ? c1v : d2;               c2i = a1 ? c1i : j;
      c1v = a0 ? c0v : (a1 ? d2 : c1v);  c1i = a0 ? c0i : (a1 ? j : c1i);
      c0v = a0 ? d2 : c0v;               c0i = a0 ? j  : c0i;
    }
  }
  float nnd[3]; int nni[3];
  #pragma unroll
  for (int r=0;r<3;r++){
    float v = c0v; int idx = c0i;
    #pragma unroll
    for (int s=1;s<64;s<<=1){
      float ov = __shfl_xor(v, s);
      int   oi = __shfl_xor(idx, s);
      bool tk = (ov < v) || (ov == v && oi < idx);
      v = tk ? ov : v; idx = tk ? oi : idx;
    }
    nnd[r] = v; nni[r] = idx;
    if (c0v == v && c0i == idx){
      c0v=c1v; c0i=c1i; c1v=c2v; c1i=c2i; c2v=3.5e38f; c2i=0x7fffffff;
    }
  }
  float w0 = fdiv_(1.0f, fmaxf(nnd[0], 1e-16f));
  float w1 = fdiv_(1.0f, fmaxf(nnd[1], 1e-16f));
  float w2 = fdiv_(1.0f, fmaxf(nnd[2], 1e-16f));
  float ws = fadd_(fadd_(w0,w1),w2);
  w0 = fdiv_(w0,ws); w1 = fdiv_(w1,ws); w2 = fdiv_(w2,ws);

  float hv = 0.0f;
  if (lane < 16){
    int c = lane;
    float x0 = Fc[(size_t)nni[0]*16 + c];
    float x1 = Fc[(size_t)nni[1]*16 + c];
    float x2 = Fc[(size_t)nni[2]*16 + c];
    hv = fadd_(fadd_(fmul_(w0,x0), fmul_(w1,x1)), fmul_(w2,x2));
  } else if (lane < 32){
    hv = Fs[(size_t)f*16 + (lane-16)];
  }
  int o1 = lane & 31;
  float acc = fmul_(__shfl(hv, 0), sW0[o1]);
  #pragma unroll
  for (int k=1;k<32;k++) acc = fmaf(__shfl(hv, k), sW0[k*32+o1], acc);
  float g1 = fmaxf(fadd_(acc, sb0[o1]), 0.0f);
  int o2 = lane & 15;
  float a2 = fmul_(__shfl(g1, 0), sW1[o2]);
  #pragma unroll
  for (int k=1;k<32;k++) a2 = fmaf(__shfl(g1, k), sW1[k*16+o2], a2);
  float g2 = fmaxf(fadd_(a2, sb1[o2]), 0.0f);

  if (!final_){
    if (lane < 16) outp[(size_t)f*16 + lane] = g2;
  } else {
    float a3 = fmul_(__shfl(g2, 0), sLW0[o2]);
    #pragma unroll
    for (int k=1;k<16;k++) a3 = fmaf(__shfl(g2, k), sLW0[k*16+o2], a3);
    float q = fmaxf(fadd_(a3, sLb0[o2]), 0.0f);
    int o3 = lane & 1;
    float a4 = fmul_(__shfl(q, 0), sLW1[o3]);
    #pragma unroll
    for (int k=1;k<16;k++) a4 = fmaf(__shfl(q, k), sLW1[k*2+o3], a4);
    a4 = fadd_(a4, sLb1[o3]);
    if (lane < 2) outp[(size_t)f*2 + lane] = a4;
  }
}

// ---------------------------------------------------------------------------
extern "C" void kernel_launch(void* const* d_in, const int* in_sizes, int n_in,
                              void* d_out, int out_size, void* d_ws, size_t ws_size,
                              hipStream_t stream) {
  (void)in_sizes; (void)n_in; (void)out_size; (void)ws_size;
  const float* x     = (const float*)d_in[0];
  const float* pos   = (const float*)d_in[1];
  const float* liW0  = (const float*)d_in[3];
  const float* lib0  = (const float*)d_in[4];
  const float* liW1  = (const float*)d_in[5];
  const float* lib1  = (const float*)d_in[6];
  const float* saW0  = (const float*)d_in[7];
  const float* sab0  = (const float*)d_in[8];
  const float* saW1  = (const float*)d_in[9];
  const float* sab1  = (const float*)d_in[10];
  const float* fpW0  = (const float*)d_in[11];
  const float* fpb0  = (const float*)d_in[12];
  const float* fpW1  = (const float*)d_in[13];
  const float* fpb1  = (const float*)d_in[14];
  const float* loW0  = (const float*)d_in[15];
  const float* lob0  = (const float*)d_in[16];
  const float* loW1  = (const float*)d_in[17];
  const float* lob1  = (const float*)d_in[18];
  float* out = (float*)d_out;

  char* ws = (char*)d_ws;
  size_t off = 0;
  auto alloc = [&](size_t bytes)->void* {
    void* p = ws + off;
    off += (bytes + 255) & ~(size_t)255;
    return p;
  };
  float4* P0 = (float4*)alloc(16384u*16);
  float4* P1 = (float4*)alloc(8192u*16);
  float4* P2 = (float4*)alloc(4096u*16);
  float4* P3 = (float4*)alloc(2048u*16);
  float*  F0 = (float*)alloc(16384u*16*4);
  float*  F1 = (float*)alloc(8192u*16*4);
  float*  F2 = (float*)alloc(4096u*16*4);
  float*  F3 = (float*)alloc(2048u*16*4);
  float*  G2 = (float*)alloc(4096u*16*4);
  float*  G1 = (float*)alloc(8192u*16*4);
  float4* S0 = (float4*)alloc(16384u*16);
  float4* S1 = (float4*)alloc(8192u*16);
  float4* S2 = (float4*)alloc(4096u*16);
  int*    R0 = (int*)alloc(256);

  k_prep<<<64,256,0,stream>>>(x,pos, liW0,lib0,liW1,lib1, P0,F0, 16384);

  // SA path (sort -> FPS -> group+conv per level)
  k_sort<<<1,1024,0,stream>>>(P0, S0, R0+0, 16384);
  k_fps10<16><<<1,1024,0,stream>>>(S0, R0+0, P1, 8192);
  k_sa<<<2048,256,0,stream>>>(P0,16384, P1, F0, saW0,      sab0,    saW1,      sab1,    F1);
  k_sort<<<1,1024,0,stream>>>(P1, S1, R0+1, 8192);
  k_fps5<8><<<1,1024,0,stream>>>(S1, R0+1, P2, 4096);
  k_sa<<<1024,256,0,stream>>>(P1, 8192, P2, F1, saW0+361,  sab0+19, saW1+304,  sab1+16, F2);
  k_sort<<<1,1024,0,stream>>>(P2, S2, R0+2, 4096);
  k_fps5<4><<<1,1024,0,stream>>>(S2, R0+2, P3, 2048);
  k_sa<<< 512,256,0,stream>>>(P2, 4096, P3, F2, saW0+722,  sab0+38, saW1+608,  sab1+32, F3);

  // FP path
  k_fp<<<1024,256,0,stream>>>(P2, P3,2048, F3, F2,
      fpW0+2048, fpb0+64, fpW1+1024, fpb1+32,
      loW0,lob0,loW1,lob1, G2, 0);
  k_fp<<<2048,256,0,stream>>>(P1, P2,4096, G2, F1,
      fpW0+1024, fpb0+32, fpW1+512,  fpb1+16,
      loW0,lob0,loW1,lob1, G1, 0);
  k_fp<<<4096,256,0,stream>>>(P0, P1,8192, G1, F0,
      fpW0,      fpb0,    fpW1,      fpb1,
      loW0,lob0,loW1,lob1, out, 1);
}